// Round 1
// baseline (224.600 us; speedup 1.0000x reference)
//
#include <hip/hip_runtime.h>
#include <hip/hip_bf16.h>

#define NB 32
#define NA 1024
#define ND 128

__device__ __forceinline__ float gelu_exact(float x) {
    return 0.5f * x * (1.0f + erff(x * 0.7071067811865476f));
}

// ---------------- clustering: one wave per batch ----------------
__global__ __launch_bounds__(64) void cluster_kernel(
    const float2* __restrict__ coords, const int* __restrict__ mask,
    int* __restrict__ assigned, int* __restrict__ gcount,
    float* __restrict__ out_mask, float* __restrict__ out_a2g)
{
    const int b = blockIdx.x;
    const int lane = threadIdx.x;
    __shared__ float2 xy[NA];

    const float2* cb = coords + b * NA;
    for (int t = 0; t < 16; ++t) {
        int a = t * 64 + lane;
        xy[a] = cb[a];
    }
    __syncthreads();

    const int base = lane * 16;
    const int* mb = mask + b * NA;

    float cx[16], cy[16];
    int asg[16];
    unsigned m = 0;
#pragma unroll
    for (int k = 0; k < 16; ++k) {
        int v = mb[base + k];
        asg[k] = v ? -1 : -2;
        m |= (v ? 1u : 0u) << k;
        cx[k] = xy[base + k].x;
        cy[k] = xy[base + k].y;
    }

    const float thr2 = 0.05f * 0.05f;
    int gid = 0;
    while (true) {
        unsigned long long bal = __ballot(m != 0u);
        if (!bal) break;
        int llane = __ffsll(bal) - 1;
        unsigned lm = (unsigned)__shfl((int)m, llane);
        int lslot = __ffs(lm) - 1;
        int lidx = llane * 16 + lslot;
        float2 lc = xy[lidx];   // broadcast LDS read
        unsigned take = 0u;
#pragma unroll
        for (int k = 0; k < 16; ++k) {
            float dx = cx[k] - lc.x;
            float dy = cy[k] - lc.y;
            float d2 = dx * dx + dy * dy;
            bool t = (d2 < thr2) && ((m >> k) & 1u);
            if (t) asg[k] = gid;
            take |= (t ? 1u : 0u) << k;
        }
        m &= ~take;
        ++gid;
    }

    int* ab = assigned + b * NA;
    float* o2 = out_a2g + b * NA;
#pragma unroll
    for (int k = 0; k < 16; ++k) {
        ab[base + k] = asg[k];
        o2[base + k] = (asg[k] == -2) ? -1.0f : (float)asg[k];
    }
    float* o1 = out_mask + b * NA;
    for (int t = 0; t < 16; ++t) {
        int g = t * 64 + lane;
        o1[g] = (g < gid) ? 1.0f : 0.0f;
    }
    if (lane == 0) gcount[b] = gid;
}

// ---------------- pooling: atomic segment sums ----------------
__global__ __launch_bounds__(256) void pool_kernel(
    const float4* __restrict__ emb, const int* __restrict__ mask,
    const int* __restrict__ assigned, float* __restrict__ sums,
    float* __restrict__ counts)
{
    int idx = blockIdx.x * 256 + threadIdx.x;   // B*A*32 threads
    int al = idx >> 5;                          // b*A + a
    int dq = idx & 31;
    if (!mask[al]) return;
    int g = assigned[al];
    int b = al >> 10;
    float4 e = emb[(size_t)al * 32 + dq];
    float* s = sums + ((size_t)((b << 10) + g)) * ND + dq * 4;
    atomicAdd(s + 0, e.x);
    atomicAdd(s + 1, e.y);
    atomicAdd(s + 2, e.z);
    atomicAdd(s + 3, e.w);
    if (dq == 0) atomicAdd(&counts[(b << 10) + g], 1.0f);
}

// ---------------- MLP(0) row, computed once (generic in b1/b2) -------------
__global__ __launch_bounds__(128) void empty_row_kernel(
    const float* __restrict__ b1, const float* __restrict__ W2,
    const float* __restrict__ b2, float* __restrict__ empty_row)
{
    __shared__ float h0[ND];
    int j = threadIdx.x;
    h0[j] = gelu_exact(b1[j]);
    __syncthreads();
    float acc = b2[j];
    for (int k = 0; k < ND; ++k) acc += h0[k] * W2[k * ND + j];
    empty_row[j] = acc;
}

// ---------------- mean + 2-layer MLP ----------------
#define TG 32
__global__ __launch_bounds__(256) void mlp_kernel(
    const float* __restrict__ sums, const float* __restrict__ counts,
    const int* __restrict__ gcount,
    const float4* __restrict__ W1, const float* __restrict__ b1,
    const float4* __restrict__ W2, const float* __restrict__ b2,
    const float* __restrict__ empty_row, float* __restrict__ out0)
{
    const int b = blockIdx.y;
    const int g0 = blockIdx.x * TG;
    const int G = gcount[b];
    const int tid = threadIdx.x;
    float* ob = out0 + ((size_t)b * NA + g0) * ND;

    if (g0 >= G) {
        // whole block past last group: rows are exactly MLP(0)
        for (int i = 0; i < 16; ++i) {
            int l = tid + i * 256;
            ob[l] = empty_row[l & 127];
        }
        return;
    }

    __shared__ float4 Wl[4096];        // 64 KB: W1 then W2
    __shared__ float tokh[TG][ND];     // 16 KB: tokens, then h

    // tokens = sums / max(cnt,1)
    for (int i = 0; i < 16; ++i) {
        int l = tid + i * 256;
        int gl = l >> 7, d = l & 127;
        float c = counts[b * NA + g0 + gl];
        tokh[gl][d] = sums[((size_t)(b * NA + g0 + gl)) * ND + d] / fmaxf(c, 1.0f);
    }
    for (int i = 0; i < 16; ++i) Wl[tid + i * 256] = W1[tid + i * 256];
    __syncthreads();

    const int jq = tid & 31;   // j0 = jq*4
    const int gs = tid >> 5;   // 0..7 -> tokens gs, gs+8, gs+16, gs+24
    float acc[4][4];

    // ---- layer 1 ----
#pragma unroll
    for (int t = 0; t < 4; ++t)
#pragma unroll
        for (int jj = 0; jj < 4; ++jj) acc[t][jj] = 0.0f;

    for (int d = 0; d < ND; ++d) {
        float4 w = Wl[d * 32 + jq];
#pragma unroll
        for (int t = 0; t < 4; ++t) {
            float tv = tokh[gs + t * 8][d];
            acc[t][0] += tv * w.x;
            acc[t][1] += tv * w.y;
            acc[t][2] += tv * w.z;
            acc[t][3] += tv * w.w;
        }
    }
    float bb0 = b1[jq * 4 + 0], bb1 = b1[jq * 4 + 1];
    float bb2 = b1[jq * 4 + 2], bb3 = b1[jq * 4 + 3];
    __syncthreads();   // all layer-1 LDS reads done
#pragma unroll
    for (int t = 0; t < 4; ++t) {
        float4 h;
        h.x = gelu_exact(acc[t][0] + bb0);
        h.y = gelu_exact(acc[t][1] + bb1);
        h.z = gelu_exact(acc[t][2] + bb2);
        h.w = gelu_exact(acc[t][3] + bb3);
        *(float4*)&tokh[gs + t * 8][jq * 4] = h;
    }
    for (int i = 0; i < 16; ++i) Wl[tid + i * 256] = W2[tid + i * 256];
    __syncthreads();

    // ---- layer 2 ----
#pragma unroll
    for (int t = 0; t < 4; ++t)
#pragma unroll
        for (int jj = 0; jj < 4; ++jj) acc[t][jj] = 0.0f;

    for (int d = 0; d < ND; ++d) {
        float4 w = Wl[d * 32 + jq];
#pragma unroll
        for (int t = 0; t < 4; ++t) {
            float tv = tokh[gs + t * 8][d];
            acc[t][0] += tv * w.x;
            acc[t][1] += tv * w.y;
            acc[t][2] += tv * w.z;
            acc[t][3] += tv * w.w;
        }
    }
    float cb0 = b2[jq * 4 + 0], cb1 = b2[jq * 4 + 1];
    float cb2 = b2[jq * 4 + 2], cb3 = b2[jq * 4 + 3];
#pragma unroll
    for (int t = 0; t < 4; ++t) {
        float4 o;
        o.x = acc[t][0] + cb0;
        o.y = acc[t][1] + cb1;
        o.z = acc[t][2] + cb2;
        o.w = acc[t][3] + cb3;
        *(float4*)&ob[(size_t)(gs + t * 8) * ND + jq * 4] = o;
    }
}

extern "C" void kernel_launch(void* const* d_in, const int* in_sizes, int n_in,
                              void* d_out, int out_size, void* d_ws, size_t ws_size,
                              hipStream_t stream) {
    const float*  emb    = (const float*)d_in[0];   // [B,A,D]
    const float2* coords = (const float2*)d_in[1];  // [B,A,2]
    const int*    mask   = (const int*)d_in[2];     // [B,A]
    const float*  W1     = (const float*)d_in[3];   // [D,D]
    const float*  b1     = (const float*)d_in[4];   // [D]
    const float*  W2     = (const float*)d_in[5];   // [D,D]
    const float*  b2     = (const float*)d_in[6];   // [D]

    float* out0 = (float*)d_out;                    // [B,A,D]
    float* out1 = out0 + (size_t)NB * NA * ND;      // group_mask
    float* out2 = out1 + (size_t)NB * NA;           // agent_to_group

    // workspace layout
    float* ws_sums   = (float*)d_ws;                       // B*A*D
    float* ws_counts = ws_sums + (size_t)NB * NA * ND;     // B*A
    int*   ws_asg    = (int*)(ws_counts + (size_t)NB * NA);// B*A
    int*   ws_gcnt   = ws_asg + (size_t)NB * NA;           // B
    float* ws_empty  = (float*)(ws_gcnt + NB);             // D

    // zero sums + counts (harness poisons ws before every launch)
    size_t zero_bytes = ((size_t)NB * NA * ND + (size_t)NB * NA) * sizeof(float);
    hipMemsetAsync(d_ws, 0, zero_bytes, stream);

    cluster_kernel<<<NB, 64, 0, stream>>>(coords, mask, ws_asg, ws_gcnt, out1, out2);
    empty_row_kernel<<<1, 128, 0, stream>>>(b1, W2, b2, ws_empty);
    pool_kernel<<<NB * NA * 32 / 256, 256, 0, stream>>>(
        (const float4*)emb, mask, ws_asg, ws_sums, ws_counts);
    dim3 grid(NA / TG, NB);
    mlp_kernel<<<grid, 256, 0, stream>>>(ws_sums, ws_counts, ws_gcnt,
                                         (const float4*)W1, b1,
                                         (const float4*)W2, b2,
                                         ws_empty, out0);
}

// Round 2
// 212.098 us; speedup vs baseline: 1.0589x; 1.0589x over previous
//
#include <hip/hip_runtime.h>
#include <hip/hip_bf16.h>

#define NB 32
#define NA 1024
#define ND 128

__device__ __forceinline__ float gelu_exact(float x) {
    return 0.5f * x * (1.0f + erff(x * 0.7071067811865476f));
}

// ---------------- clustering: one wave per batch, readlane broadcast ----------
__global__ __launch_bounds__(64) void cluster_kernel(
    const float* __restrict__ coords, const int* __restrict__ mask,
    int* __restrict__ assigned, int* __restrict__ gcount,
    float* __restrict__ out_mask, float* __restrict__ out_a2g)
{
    const int b = blockIdx.x;
    const int lane = threadIdx.x;

    // each lane owns agents [lane*16, lane*16+16)
    float2 cxy[16];
    {
        const float4* c4 = (const float4*)(coords + (size_t)b * NA * 2) + lane * 8;
#pragma unroll
        for (int q = 0; q < 8; ++q) {
            float4 v = c4[q];
            cxy[2 * q + 0] = make_float2(v.x, v.y);
            cxy[2 * q + 1] = make_float2(v.z, v.w);
        }
    }
    unsigned m = 0;
    int asg[16];
    {
        const int4* m4 = (const int4*)(mask + b * NA) + lane * 4;
#pragma unroll
        for (int q = 0; q < 4; ++q) {
            int4 v = m4[q];
            int k = q * 4;
            asg[k + 0] = v.x ? -1 : -2;  m |= (v.x ? 1u : 0u) << (k + 0);
            asg[k + 1] = v.y ? -1 : -2;  m |= (v.y ? 1u : 0u) << (k + 1);
            asg[k + 2] = v.z ? -1 : -2;  m |= (v.z ? 1u : 0u) << (k + 2);
            asg[k + 3] = v.w ? -1 : -2;  m |= (v.w ? 1u : 0u) << (k + 3);
        }
    }

    const float thr2 = 0.05f * 0.05f;
    int gid = 0;
    while (true) {
        unsigned long long bal = __ballot(m != 0u);
        if (!bal) break;
        // per-lane candidate = coords of own lowest unassigned slot (cndmask tree)
        int f = __builtin_ctz(m | 0x10000u);
        float2 c01 = (f & 1) ? cxy[1]  : cxy[0];
        float2 c23 = (f & 1) ? cxy[3]  : cxy[2];
        float2 c45 = (f & 1) ? cxy[5]  : cxy[4];
        float2 c67 = (f & 1) ? cxy[7]  : cxy[6];
        float2 c89 = (f & 1) ? cxy[9]  : cxy[8];
        float2 cab = (f & 1) ? cxy[11] : cxy[10];
        float2 ccd = (f & 1) ? cxy[13] : cxy[12];
        float2 cef = (f & 1) ? cxy[15] : cxy[14];
        float2 q0 = (f & 2) ? c23 : c01;
        float2 q1 = (f & 2) ? c67 : c45;
        float2 q2 = (f & 2) ? cab : c89;
        float2 q3 = (f & 2) ? cef : ccd;
        float2 h0 = (f & 4) ? q1 : q0;
        float2 h1 = (f & 4) ? q3 : q2;
        float2 cand = (f & 8) ? h1 : h0;

        int llane = (int)__builtin_ctzll(bal);     // wave-uniform (SGPR)
        float lx = __builtin_bit_cast(float,
            __builtin_amdgcn_readlane(__builtin_bit_cast(int, cand.x), llane));
        float ly = __builtin_bit_cast(float,
            __builtin_amdgcn_readlane(__builtin_bit_cast(int, cand.y), llane));

        unsigned take = 0u;
#pragma unroll
        for (int k = 0; k < 16; ++k) {
            float dx = cxy[k].x - lx;
            float dy = cxy[k].y - ly;
            // match reference exactly: dx*dx + dy*dy, no fma contraction
            float d2 = __fadd_rn(__fmul_rn(dx, dx), __fmul_rn(dy, dy));
            bool t = (d2 < thr2) && ((m >> k) & 1u);
            if (t) asg[k] = gid;
            take |= (t ? 1u : 0u) << k;
        }
        m &= ~take;
        ++gid;
    }

    // write assigned + agent_to_group (vectorized)
    {
        int4* ab = (int4*)(assigned + b * NA) + lane * 4;
        float4* o2 = (float4*)(out_a2g + b * NA) + lane * 4;
#pragma unroll
        for (int q = 0; q < 4; ++q) {
            int k = q * 4;
            ab[q] = make_int4(asg[k], asg[k + 1], asg[k + 2], asg[k + 3]);
            float4 v;
            v.x = (asg[k + 0] == -2) ? -1.0f : (float)asg[k + 0];
            v.y = (asg[k + 1] == -2) ? -1.0f : (float)asg[k + 1];
            v.z = (asg[k + 2] == -2) ? -1.0f : (float)asg[k + 2];
            v.w = (asg[k + 3] == -2) ? -1.0f : (float)asg[k + 3];
            o2[q] = v;
        }
    }
    float* o1 = out_mask + b * NA;
    for (int t = 0; t < 16; ++t) {
        int g = t * 64 + lane;
        o1[g] = (g < gid) ? 1.0f : 0.0f;
    }
    if (lane == 0) gcount[b] = gid;
}

// ---------------- pooling: LDS segment sums, one block per (batch, d-quad) ---
__global__ __launch_bounds__(256) void pool_kernel(
    const float4* __restrict__ emb, const int* __restrict__ assigned,
    const int* __restrict__ gcount,
    float4* __restrict__ sums, float* __restrict__ counts)
{
    const int dq = blockIdx.x;   // 0..31 (d-quad)
    const int b  = blockIdx.y;   // 0..31
    const int tid = threadIdx.x;
    __shared__ float4 ls[NA];
    __shared__ float  lc[NA];
    for (int i = tid; i < NA; i += 256) {
        ls[i] = make_float4(0.f, 0.f, 0.f, 0.f);
        lc[i] = 0.f;
    }
    __syncthreads();

    const int* ab = assigned + (b << 10);
    const float4* eb = emb + ((size_t)(b << 10)) * 32 + dq;
    for (int a = tid; a < NA; a += 256) {
        int g = ab[a];
        if (g >= 0) {
            float4 e = eb[(size_t)a * 32];
            atomicAdd(&ls[g].x, e.x);
            atomicAdd(&ls[g].y, e.y);
            atomicAdd(&ls[g].z, e.z);
            atomicAdd(&ls[g].w, e.w);
            if (dq == 0) atomicAdd(&lc[g], 1.0f);
        }
    }
    __syncthreads();

    const int Gc = (gcount[b] + 31) & ~31;   // only groups the MLP will read
    for (int g = tid; g < Gc; g += 256) {
        sums[(((size_t)(b << 10)) + g) * 32 + dq] = ls[g];
        if (dq == 0) counts[(b << 10) + g] = lc[g];
    }
}

// ---------------- mean + 2-layer MLP (fast path computes MLP(0) locally) -----
#define TG 32
__global__ __launch_bounds__(256) void mlp_kernel(
    const float* __restrict__ sums, const float* __restrict__ counts,
    const int* __restrict__ gcount,
    const float* __restrict__ W1, const float* __restrict__ b1,
    const float* __restrict__ W2, const float* __restrict__ b2,
    float* __restrict__ out0)
{
    const int b = blockIdx.y;
    const int g0 = blockIdx.x * TG;
    const int G = gcount[b];
    const int tid = threadIdx.x;
    float* ob = out0 + ((size_t)b * NA + g0) * ND;

    __shared__ float4 Wl[4096];        // 64 KB
    __shared__ float tokh[TG][ND];     // 16 KB (also reused by fast path)

    if (g0 >= G) {
        // rows are exactly MLP(0): h0 = gelu(b1); row = h0 @ W2 + b2
        float* h0 = &tokh[0][0];
        float* row = &tokh[8][0];
        if (tid < ND) h0[tid] = gelu_exact(b1[tid]);
        __syncthreads();
        if (tid < ND) {
            float acc = b2[tid];
            for (int k = 0; k < ND; ++k) acc += h0[k] * W2[k * ND + tid];
            row[tid] = acc;
        }
        __syncthreads();
        float4* ob4 = (float4*)ob;
        const float4* r4 = (const float4*)row;
#pragma unroll
        for (int i = 0; i < 4; ++i) {
            int l = tid + i * 256;
            ob4[l] = r4[l & 31];
        }
        return;
    }

    // tokens = sums / max(cnt,1)
    for (int i = 0; i < 16; ++i) {
        int l = tid + i * 256;
        int gl = l >> 7, d = l & 127;
        float c = counts[b * NA + g0 + gl];
        tokh[gl][d] = sums[((size_t)(b * NA + g0 + gl)) * ND + d] / fmaxf(c, 1.0f);
    }
    const float4* W14 = (const float4*)W1;
    for (int i = 0; i < 16; ++i) Wl[tid + i * 256] = W14[tid + i * 256];
    __syncthreads();

    const int jq = tid & 31;   // output quad j = jq*4
    const int gs = tid >> 5;   // token rows gs, gs+8, gs+16, gs+24
    float acc[4][4];

    // ---- layer 1 ----
#pragma unroll
    for (int t = 0; t < 4; ++t)
#pragma unroll
        for (int jj = 0; jj < 4; ++jj) acc[t][jj] = 0.0f;

    for (int d = 0; d < ND; ++d) {
        float4 w = Wl[d * 32 + jq];
#pragma unroll
        for (int t = 0; t < 4; ++t) {
            float tv = tokh[gs + t * 8][d];
            acc[t][0] += tv * w.x;
            acc[t][1] += tv * w.y;
            acc[t][2] += tv * w.z;
            acc[t][3] += tv * w.w;
        }
    }
    float bb0 = b1[jq * 4 + 0], bb1 = b1[jq * 4 + 1];
    float bb2 = b1[jq * 4 + 2], bb3 = b1[jq * 4 + 3];
    __syncthreads();
#pragma unroll
    for (int t = 0; t < 4; ++t) {
        float4 h;
        h.x = gelu_exact(acc[t][0] + bb0);
        h.y = gelu_exact(acc[t][1] + bb1);
        h.z = gelu_exact(acc[t][2] + bb2);
        h.w = gelu_exact(acc[t][3] + bb3);
        *(float4*)&tokh[gs + t * 8][jq * 4] = h;
    }
    const float4* W24 = (const float4*)W2;
    for (int i = 0; i < 16; ++i) Wl[tid + i * 256] = W24[tid + i * 256];
    __syncthreads();

    // ---- layer 2 ----
#pragma unroll
    for (int t = 0; t < 4; ++t)
#pragma unroll
        for (int jj = 0; jj < 4; ++jj) acc[t][jj] = 0.0f;

    for (int d = 0; d < ND; ++d) {
        float4 w = Wl[d * 32 + jq];
#pragma unroll
        for (int t = 0; t < 4; ++t) {
            float tv = tokh[gs + t * 8][d];
            acc[t][0] += tv * w.x;
            acc[t][1] += tv * w.y;
            acc[t][2] += tv * w.z;
            acc[t][3] += tv * w.w;
        }
    }
    float cb0 = b2[jq * 4 + 0], cb1 = b2[jq * 4 + 1];
    float cb2 = b2[jq * 4 + 2], cb3 = b2[jq * 4 + 3];
#pragma unroll
    for (int t = 0; t < 4; ++t) {
        float4 o;
        o.x = acc[t][0] + cb0;
        o.y = acc[t][1] + cb1;
        o.z = acc[t][2] + cb2;
        o.w = acc[t][3] + cb3;
        *(float4*)&ob[(size_t)(gs + t * 8) * ND + jq * 4] = o;
    }
}

extern "C" void kernel_launch(void* const* d_in, const int* in_sizes, int n_in,
                              void* d_out, int out_size, void* d_ws, size_t ws_size,
                              hipStream_t stream) {
    const float* emb    = (const float*)d_in[0];   // [B,A,D]
    const float* coords = (const float*)d_in[1];   // [B,A,2]
    const int*   mask   = (const int*)d_in[2];     // [B,A]
    const float* W1     = (const float*)d_in[3];   // [D,D]
    const float* b1     = (const float*)d_in[4];   // [D]
    const float* W2     = (const float*)d_in[5];   // [D,D]
    const float* b2     = (const float*)d_in[6];   // [D]

    float* out0 = (float*)d_out;                    // [B,A,D]
    float* out1 = out0 + (size_t)NB * NA * ND;      // group_mask
    float* out2 = out1 + (size_t)NB * NA;           // agent_to_group

    // workspace layout (no memset needed: pool fully writes what mlp reads)
    float* ws_sums   = (float*)d_ws;                        // B*A*D
    float* ws_counts = ws_sums + (size_t)NB * NA * ND;      // B*A
    int*   ws_asg    = (int*)(ws_counts + (size_t)NB * NA); // B*A
    int*   ws_gcnt   = ws_asg + (size_t)NB * NA;            // B

    cluster_kernel<<<NB, 64, 0, stream>>>(coords, mask, ws_asg, ws_gcnt, out1, out2);
    pool_kernel<<<dim3(32, NB), 256, 0, stream>>>(
        (const float4*)emb, ws_asg, ws_gcnt, (float4*)ws_sums, ws_counts);
    mlp_kernel<<<dim3(NA / TG, NB), 256, 0, stream>>>(
        ws_sums, ws_counts, ws_gcnt, W1, b1, W2, b2, out0);
}